// Round 2
// baseline (2614.966 us; speedup 1.0000x reference)
//
#include <hip/hip_runtime.h>

#define BATCH 16
#define NXCD 8

// Physical chiplet id of the executing wave (gfx940+: HW_REG_XCC_ID).
static __device__ __forceinline__ int xcc_id() {
    unsigned x;
    asm volatile("s_getreg_b32 %0, hwreg(HW_REG_XCC_ID)" : "=s"(x));
    return (int)(x & 7u);
}

// Build aux_T[(N+1)][16]: node-major transpose of x with a zero row at node 0.
__global__ void build_aux_T(const float* __restrict__ x, float* __restrict__ auxT, int n) {
    int idx = blockIdx.x * blockDim.x + threadIdx.x;  // over B*n, x-coalesced
    int total = BATCH * n;
    if (idx >= total) return;
    int b = idx / n;
    int i = idx % n;
    auxT[(i + 1) * BATCH + b] = x[idx];
    if (idx < BATCH) auxT[idx] = 0.0f;  // node-0 zero row
}

// One thread per edge; accumulate into the XCD-local copy with L2-scope atomics.
__global__ void edge_kernel_xcd(const float* __restrict__ param,
                                const int* __restrict__ src,
                                const int* __restrict__ des,
                                const float* __restrict__ auxT,
                                float* __restrict__ outBase,
                                int E, size_t copyElems) {
    int e = blockIdx.x * blockDim.x + threadIdx.x;
    if (e >= E) return;
    // All blocks physically resident on XCD k share one L2 -> workgroup-scope
    // (non-sc1) atomics into copy k are coherent among them.
    float* outT = outBase + (size_t)xcc_id() * copyElems;

    float a = param[e];
    float w = param[E + e];
    float c = param[2 * E + e];
    int s = src[e];
    int d = des[e];
    const float4* vs4 = (const float4*)(auxT + (size_t)s * BATCH);
    const float4* vd4 = (const float4*)(auxT + (size_t)d * BATCH);
    float* os = outT + (size_t)s * BATCH;
    float* od = outT + (size_t)d * BATCH;
#pragma unroll
    for (int q = 0; q < 4; ++q) {
        float4 vs = vs4[q];
        float4 vd = vd4[q];
        float st[4];
        st[0] = a * tanhf(w * (vs.x - vd.x) + c);
        st[1] = a * tanhf(w * (vs.y - vd.y) + c);
        st[2] = a * tanhf(w * (vs.z - vd.z) + c);
        st[3] = a * tanhf(w * (vs.w - vd.w) + c);
#pragma unroll
        for (int j = 0; j < 4; ++j) {
            __hip_atomic_fetch_add(os + q * 4 + j, -st[j], __ATOMIC_RELAXED,
                                   __HIP_MEMORY_SCOPE_WORKGROUP);
            __hip_atomic_fetch_add(od + q * 4 + j, st[j], __ATOMIC_RELAXED,
                                   __HIP_MEMORY_SCOPE_WORKGROUP);
        }
    }
}

// out[b][i] = sum_k copies[k][(i+1)*16 + b]  (drops node 0, writes all of d_out)
__global__ void reduce_out(const float* __restrict__ outBase, float* __restrict__ out,
                           int n, size_t copyElems) {
    int idx = blockIdx.x * blockDim.x + threadIdx.x;  // out-coalesced
    if (idx >= BATCH * n) return;
    int b = idx / n;
    int i = idx % n;
    size_t off = (size_t)(i + 1) * BATCH + b;
    float sum = 0.0f;
#pragma unroll
    for (int k = 0; k < NXCD; ++k) sum += outBase[(size_t)k * copyElems + off];
    out[idx] = sum;
}

// --- fallback path (single copy, device-scope atomics), from round 1 ---
__global__ void edge_kernel(const float* __restrict__ param,
                            const int* __restrict__ src,
                            const int* __restrict__ des,
                            const float* __restrict__ auxT,
                            float* __restrict__ outT,
                            int E) {
    int e = blockIdx.x * blockDim.x + threadIdx.x;
    if (e >= E) return;
    float a = param[e];
    float w = param[E + e];
    float c = param[2 * E + e];
    int s = src[e];
    int d = des[e];
    const float4* vs4 = (const float4*)(auxT + (size_t)s * BATCH);
    const float4* vd4 = (const float4*)(auxT + (size_t)d * BATCH);
    float* os = outT + (size_t)s * BATCH;
    float* od = outT + (size_t)d * BATCH;
#pragma unroll
    for (int q = 0; q < 4; ++q) {
        float4 vs = vs4[q];
        float4 vd = vd4[q];
        float4 st;
        st.x = a * tanhf(w * (vs.x - vd.x) + c);
        st.y = a * tanhf(w * (vs.y - vd.y) + c);
        st.z = a * tanhf(w * (vs.z - vd.z) + c);
        st.w = a * tanhf(w * (vs.w - vd.w) + c);
        atomicAdd(os + q * 4 + 0, -st.x);
        atomicAdd(os + q * 4 + 1, -st.y);
        atomicAdd(os + q * 4 + 2, -st.z);
        atomicAdd(os + q * 4 + 3, -st.w);
        atomicAdd(od + q * 4 + 0, st.x);
        atomicAdd(od + q * 4 + 1, st.y);
        atomicAdd(od + q * 4 + 2, st.z);
        atomicAdd(od + q * 4 + 3, st.w);
    }
}

__global__ void write_out(const float* __restrict__ outT, float* __restrict__ out, int n) {
    int idx = blockIdx.x * blockDim.x + threadIdx.x;
    if (idx >= BATCH * n) return;
    int b = idx / n;
    int i = idx % n;
    out[idx] = outT[(size_t)(i + 1) * BATCH + b];
}

__global__ void edge_direct(const float* __restrict__ param,
                            const int* __restrict__ src,
                            const int* __restrict__ des,
                            const float* __restrict__ x,
                            float* __restrict__ out,
                            int E, int n) {
    int e = blockIdx.x * blockDim.x + threadIdx.x;
    if (e >= E) return;
    float a = param[e];
    float w = param[E + e];
    float c = param[2 * E + e];
    int s = src[e];
    int d = des[e];
#pragma unroll
    for (int b = 0; b < BATCH; ++b) {
        float vs = s ? x[(size_t)b * n + (s - 1)] : 0.0f;
        float vd = d ? x[(size_t)b * n + (d - 1)] : 0.0f;
        float st = a * tanhf(w * (vs - vd) + c);
        if (s) atomicAdd(out + (size_t)b * n + (s - 1), -st);
        if (d) atomicAdd(out + (size_t)b * n + (d - 1), st);
    }
}

extern "C" void kernel_launch(void* const* d_in, const int* in_sizes, int n_in,
                              void* d_out, int out_size, void* d_ws, size_t ws_size,
                              hipStream_t stream) {
    const float* x     = (const float*)d_in[1];
    const float* param = (const float*)d_in[2];
    const int*   src   = (const int*)d_in[3];
    const int*   des   = (const int*)d_in[4];
    float* out = (float*)d_out;

    int E = in_sizes[3];
    int n = in_sizes[1] / BATCH;  // N = 50000

    size_t copyElems = (size_t)(n + 1) * BATCH;
    size_t auxBytes  = copyElems * sizeof(float);
    int totalX = BATCH * n;

    if (ws_size >= auxBytes * (1 + NXCD)) {
        // XCD-local L2-atomic path
        float* auxT    = (float*)d_ws;
        float* outBase = auxT + copyElems;

        hipMemsetAsync(outBase, 0, auxBytes * NXCD, stream);
        build_aux_T<<<(totalX + 255) / 256, 256, 0, stream>>>(x, auxT, n);
        edge_kernel_xcd<<<(E + 255) / 256, 256, 0, stream>>>(param, src, des, auxT,
                                                             outBase, E, copyElems);
        reduce_out<<<(totalX + 255) / 256, 256, 0, stream>>>(outBase, out, n, copyElems);
    } else if (ws_size >= auxBytes * 2) {
        // single-copy device-scope atomic path
        float* auxT = (float*)d_ws;
        float* outT = auxT + copyElems;
        hipMemsetAsync(outT, 0, auxBytes, stream);
        build_aux_T<<<(totalX + 255) / 256, 256, 0, stream>>>(x, auxT, n);
        edge_kernel<<<(E + 255) / 256, 256, 0, stream>>>(param, src, des, auxT, outT, E);
        write_out<<<(totalX + 255) / 256, 256, 0, stream>>>(outT, out, n);
    } else {
        hipMemsetAsync(out, 0, (size_t)out_size * sizeof(float), stream);
        edge_direct<<<(E + 255) / 256, 256, 0, stream>>>(param, src, des, x, out, E, n);
    }
}

// Round 3
// 583.321 us; speedup vs baseline: 4.4829x; 4.4829x over previous
//
#include <hip/hip_runtime.h>

#define BATCH 16
#define PS 896          // nodes per partition (LDS acc = 896*16*4 = 57344 B)
#define NPART 56        // ceil(50001/896)
#define QCAP 768        // LDS match-queue entries (uint2 = 8B each)
#define SCAN_THREADS 1024
#define EPT 4           // edges per thread per scan iteration

// fast tanh: 1 - 2/(e^{2z}+1); rel err ~1e-6, fine vs 2.6e-4 threshold
static __device__ __forceinline__ float fast_tanh(float z) {
    float ez = __expf(2.0f * z);
    return 1.0f - 2.0f * __builtin_amdgcn_rcpf(ez + 1.0f);
}

// Build aux_T[(N+1)][16]: node-major transpose of x with a zero row at node 0.
__global__ void build_aux_T(const float* __restrict__ x, float* __restrict__ auxT, int n) {
    int idx = blockIdx.x * blockDim.x + threadIdx.x;
    if (idx >= BATCH * n) return;
    int b = idx / n;
    int i = idx % n;
    auxT[(i + 1) * BATCH + b] = x[idx];
    if (idx < BATCH) auxT[idx] = 0.0f;
}

// Block (p,k): accumulate partition p's node rows over edge chunk k into LDS,
// using ballot-compacted queue + 16-lane-per-edge drain. No global atomics.
__global__ __launch_bounds__(SCAN_THREADS)
void scan_partition(const float* __restrict__ param,
                    const int* __restrict__ src,
                    const int* __restrict__ des,
                    const float* __restrict__ auxT,
                    float* __restrict__ partials,
                    int E, int Bp) {
    __shared__ float acc[PS * BATCH];
    __shared__ uint2 queue[QCAP];
    __shared__ int qc[2];

    const int p = blockIdx.x / Bp;
    const int k = blockIdx.x - p * Bp;
    const int base = p * PS;
    const int tid = threadIdx.x;
    const int lane = tid & 63;

    for (int i = tid; i < PS * BATCH; i += SCAN_THREADS) acc[i] = 0.0f;
    if (tid < 2) qc[tid] = 0;
    __syncthreads();

    const int chunkE = (((E + Bp - 1) / Bp) + 3) & ~3;
    const int start = k * chunkE;
    const int end = min(start + chunkE, E);
    const int iters = (chunkE + SCAN_THREADS * EPT - 1) / (SCAN_THREADS * EPT);

    int par = 0;
    for (int it = 0; it < iters; ++it) {
        // ---- push phase ----
        int e0 = start + it * SCAN_THREADS * EPT + tid * EPT;
        int s4[EPT], d4[EPT];
        int nval = 0;
        if (e0 + EPT <= end) {
            int4 sv = *(const int4*)(src + e0);
            int4 dv = *(const int4*)(des + e0);
            s4[0] = sv.x; s4[1] = sv.y; s4[2] = sv.z; s4[3] = sv.w;
            d4[0] = dv.x; d4[1] = dv.y; d4[2] = dv.z; d4[3] = dv.w;
            nval = EPT;
        } else if (e0 < end) {
            nval = end - e0;
            for (int j = 0; j < nval; ++j) { s4[j] = src[e0 + j]; d4[j] = des[e0 + j]; }
        }
#pragma unroll
        for (int j = 0; j < EPT; ++j) {
            int s = s4[j], d = d4[j];
            bool ms = (j < nval) && ((unsigned)(s - base) < (unsigned)PS);
            bool md = (j < nval) && ((unsigned)(d - base) < (unsigned)PS);
            bool m = ms || md;
            unsigned long long mask = __ballot(m);
            if (mask) {
                int leader = __ffsll((long long)mask) - 1;
                int cnt = __popcll(mask);
                int qbase = 0;
                if (lane == leader) qbase = atomicAdd(&qc[par], cnt);
                qbase = __shfl(qbase, leader);
                if (m) {
                    int pos = qbase + __popcll(mask & ((1ull << lane) - 1ull));
                    if (pos < QCAP) {
                        int e = e0 + j;
                        unsigned idf = (unsigned)e | (ms ? 1u << 30 : 0u) | (md ? 1u << 31 : 0u);
                        queue[pos] = make_uint2(idf, (unsigned)s | ((unsigned)d << 16));
                    } else {
                        // overflow: process inline (rare)
                        int e = e0 + j;
                        float a = param[e], w = param[E + e], cc = param[2 * E + e];
                        for (int b = 0; b < BATCH; ++b) {
                            float vs = auxT[s * BATCH + b];
                            float vd = auxT[d * BATCH + b];
                            float st = a * fast_tanh(w * (vs - vd) + cc);
                            if (ms) atomicAdd(&acc[(s - base) * BATCH + b], -st);
                            if (md) atomicAdd(&acc[(d - base) * BATCH + b], st);
                        }
                    }
                }
            }
        }
        __syncthreads();
        // ---- drain phase ----
        if (tid == 0) qc[par ^ 1] = 0;   // reset the other counter for next iter
        int Q = min(qc[par], QCAP);
        int group = tid >> 4;            // 64 groups of 16 lanes
        int b = tid & 15;
        for (int q = group; q < Q; q += SCAN_THREADS / 16) {
            uint2 r = queue[q];
            int s = (int)(r.y & 0xFFFFu);
            int d = (int)(r.y >> 16);
            int e = (int)(r.x & 0x0FFFFFFFu);
            float a = param[e], w = param[E + e], cc = param[2 * E + e];
            float vs = auxT[s * BATCH + b];
            float vd = auxT[d * BATCH + b];
            float st = a * fast_tanh(w * (vs - vd) + cc);
            if (r.x & (1u << 30)) atomicAdd(&acc[(s - base) * BATCH + b], -st);
            if (r.x & (1u << 31)) atomicAdd(&acc[(d - base) * BATCH + b], st);
        }
        __syncthreads();
        par ^= 1;
    }

    // write partial (coalesced)
    float* myPart = partials + (size_t)blockIdx.x * (PS * BATCH);
    for (int i = tid; i < PS * BATCH; i += SCAN_THREADS) myPart[i] = acc[i];
}

// out[b][j] = sum_k partials[(p*Bp+k)][local][b], node i=j+1 (drops node 0)
__global__ void reduce_partials(const float* __restrict__ partials,
                                float* __restrict__ out, int n, int Bp) {
    int idx = blockIdx.x * blockDim.x + threadIdx.x;
    if (idx >= BATCH * n) return;
    int b = idx / n;
    int j = idx % n;
    int i = j + 1;
    int p = i / PS;
    int local = i - p * PS;
    size_t off = (size_t)local * BATCH + b;
    const float* basep = partials + (size_t)p * Bp * (PS * BATCH);
    float sum = 0.0f;
    for (int k = 0; k < Bp; ++k) sum += basep[(size_t)k * (PS * BATCH) + off];
    out[idx] = sum;
}

// ---------- fallback path (round-1): single accumulator, device atomics ----------
__global__ void edge_kernel(const float* __restrict__ param,
                            const int* __restrict__ src,
                            const int* __restrict__ des,
                            const float* __restrict__ auxT,
                            float* __restrict__ outT, int E) {
    int e = blockIdx.x * blockDim.x + threadIdx.x;
    if (e >= E) return;
    float a = param[e], w = param[E + e], c = param[2 * E + e];
    int s = src[e], d = des[e];
    const float4* vs4 = (const float4*)(auxT + (size_t)s * BATCH);
    const float4* vd4 = (const float4*)(auxT + (size_t)d * BATCH);
    float* os = outT + (size_t)s * BATCH;
    float* od = outT + (size_t)d * BATCH;
#pragma unroll
    for (int q = 0; q < 4; ++q) {
        float4 vs = vs4[q], vd = vd4[q];
        float st[4];
        st[0] = a * tanhf(w * (vs.x - vd.x) + c);
        st[1] = a * tanhf(w * (vs.y - vd.y) + c);
        st[2] = a * tanhf(w * (vs.z - vd.z) + c);
        st[3] = a * tanhf(w * (vs.w - vd.w) + c);
#pragma unroll
        for (int j = 0; j < 4; ++j) {
            atomicAdd(os + q * 4 + j, -st[j]);
            atomicAdd(od + q * 4 + j, st[j]);
        }
    }
}

__global__ void write_out(const float* __restrict__ outT, float* __restrict__ out, int n) {
    int idx = blockIdx.x * blockDim.x + threadIdx.x;
    if (idx >= BATCH * n) return;
    int b = idx / n;
    int i = idx % n;
    out[idx] = outT[(size_t)(i + 1) * BATCH + b];
}

__global__ void edge_direct(const float* __restrict__ param,
                            const int* __restrict__ src,
                            const int* __restrict__ des,
                            const float* __restrict__ x,
                            float* __restrict__ out, int E, int n) {
    int e = blockIdx.x * blockDim.x + threadIdx.x;
    if (e >= E) return;
    float a = param[e], w = param[E + e], c = param[2 * E + e];
    int s = src[e], d = des[e];
#pragma unroll
    for (int b = 0; b < BATCH; ++b) {
        float vs = s ? x[(size_t)b * n + (s - 1)] : 0.0f;
        float vd = d ? x[(size_t)b * n + (d - 1)] : 0.0f;
        float st = a * tanhf(w * (vs - vd) + c);
        if (s) atomicAdd(out + (size_t)b * n + (s - 1), -st);
        if (d) atomicAdd(out + (size_t)b * n + (d - 1), st);
    }
}

extern "C" void kernel_launch(void* const* d_in, const int* in_sizes, int n_in,
                              void* d_out, int out_size, void* d_ws, size_t ws_size,
                              hipStream_t stream) {
    const float* x     = (const float*)d_in[1];
    const float* param = (const float*)d_in[2];
    const int*   src   = (const int*)d_in[3];
    const int*   des   = (const int*)d_in[4];
    float* out = (float*)d_out;

    int E = in_sizes[3];
    int n = in_sizes[1] / BATCH;   // N = 50000

    size_t auxBytes = (size_t)(n + 1) * BATCH * sizeof(float);
    size_t partialBytesPerBlockSet = (size_t)NPART * PS * BATCH * sizeof(float); // per Bp unit
    int total = BATCH * n;

    int Bp = 0;
    if (ws_size > auxBytes)
        Bp = (int)((ws_size - auxBytes) / partialBytesPerBlockSet);
    if (Bp > 10) Bp = 10;

    if (Bp >= 1 && (n + 1) <= NPART * PS) {
        float* auxT = (float*)d_ws;
        float* partials = auxT + (size_t)(n + 1) * BATCH;

        build_aux_T<<<(total + 255) / 256, 256, 0, stream>>>(x, auxT, n);
        scan_partition<<<NPART * Bp, SCAN_THREADS, 0, stream>>>(param, src, des,
                                                                auxT, partials, E, Bp);
        reduce_partials<<<(total + 255) / 256, 256, 0, stream>>>(partials, out, n, Bp);
    } else if (ws_size >= auxBytes * 2) {
        float* auxT = (float*)d_ws;
        float* outT = auxT + (size_t)(n + 1) * BATCH;
        hipMemsetAsync(outT, 0, auxBytes, stream);
        build_aux_T<<<(total + 255) / 256, 256, 0, stream>>>(x, auxT, n);
        edge_kernel<<<(E + 255) / 256, 256, 0, stream>>>(param, src, des, auxT, outT, E);
        write_out<<<(total + 255) / 256, 256, 0, stream>>>(outT, out, n);
    } else {
        hipMemsetAsync(out, 0, (size_t)out_size * sizeof(float), stream);
        edge_direct<<<(E + 255) / 256, 256, 0, stream>>>(param, src, des, x, out, E, n);
    }
}

// Round 4
// 440.438 us; speedup vs baseline: 5.9372x; 1.3244x over previous
//
#include <hip/hip_runtime.h>

#define BATCH 16
#define PS 896          // nodes per partition (LDS acc = 896*16*4 = 57344 B)
#define NPART 56        // ceil(50001/896)
#define SLICES 8        // accumulate blocks per partition
#define NB (NPART * SLICES)   // 448 blocks for hist/scatter/accumulate
#define TPB 1024

// fast tanh: 1 - 2/(e^{2z}+1); rel err ~1e-6 vs 2.6e-4 threshold
static __device__ __forceinline__ float fast_tanh(float z) {
    float ez = __expf(2.0f * z);
    return 1.0f - 2.0f * __builtin_amdgcn_rcpf(ez + 1.0f);
}

// aux_T[(N+1)][16]: node-major transpose of x with a zero row at node 0.
__global__ void build_aux_T(const float* __restrict__ x, float* __restrict__ auxT, int n) {
    int idx = blockIdx.x * blockDim.x + threadIdx.x;
    if (idx >= BATCH * n) return;
    int b = idx / n;
    int i = idx % n;
    auxT[(i + 1) * BATCH + b] = x[idx];
    if (idx < BATCH) auxT[idx] = 0.0f;
}

// ---------------- sorted-record path ----------------

__global__ __launch_bounds__(TPB)
void hist_kernel(const int* __restrict__ src, const int* __restrict__ des,
                 unsigned* __restrict__ blockHist, int E) {
    __shared__ unsigned hist[NPART];
    int tid = threadIdx.x;
    for (int i = tid; i < NPART; i += TPB) hist[i] = 0;
    __syncthreads();
    long t = (long)blockIdx.x * TPB + tid;
    long stride = (long)gridDim.x * TPB * 4;
    for (long e0 = t * 4; e0 < E; e0 += stride) {
        int ne = (int)min((long)4, (long)E - e0);
        if (ne == 4) {
            int4 sv = *(const int4*)(src + e0);
            int4 dv = *(const int4*)(des + e0);
            int ss[4] = {sv.x, sv.y, sv.z, sv.w};
            int dd[4] = {dv.x, dv.y, dv.z, dv.w};
#pragma unroll
            for (int j = 0; j < 4; ++j) {
                int ps = ss[j] / PS, pd = dd[j] / PS;
                atomicAdd(&hist[ps], 1u);
                if (pd != ps) atomicAdd(&hist[pd], 1u);
            }
        } else {
            for (int j = 0; j < ne; ++j) {
                int ps = src[e0 + j] / PS, pd = des[e0 + j] / PS;
                atomicAdd(&hist[ps], 1u);
                if (pd != ps) atomicAdd(&hist[pd], 1u);
            }
        }
    }
    __syncthreads();
    if (tid < NPART) blockHist[(size_t)blockIdx.x * NPART + tid] = hist[tid];
}

// One block: exact scatter offsets per (block, partition). NB must be /16.
__global__ __launch_bounds__(TPB)
void scan_offsets(const unsigned* __restrict__ blockHist, unsigned* __restrict__ offsets,
                  unsigned* __restrict__ binStartG, unsigned* __restrict__ binTotalG) {
    __shared__ unsigned tot[NPART];
    __shared__ unsigned bstart[NPART];
    int tid = threadIdx.x;
    int team = tid >> 4, j = tid & 15;
    // phase 1: per-partition totals (team = partition)
    if (team < NPART) {
        unsigned lsum = 0;
        for (int b = j; b < NB; b += 16) lsum += blockHist[(size_t)b * NPART + team];
        for (int m = 1; m < 16; m <<= 1) lsum += __shfl_xor(lsum, m, 64);
        if (j == 0) tot[team] = lsum;
    }
    __syncthreads();
    if (tid == 0) {
        unsigned run = 0;
        for (int p = 0; p < NPART; ++p) { bstart[p] = run; run += tot[p]; }
    }
    __syncthreads();
    if (tid < NPART) { binStartG[tid] = bstart[tid]; binTotalG[tid] = tot[tid]; }
    // phase 2: blocked exclusive scan over blocks within each partition
    if (team < NPART) {
        const int per = NB / 16;   // 28
        unsigned ls = 0;
        for (int b = j * per; b < (j + 1) * per; ++b)
            ls += blockHist[(size_t)b * NPART + team];
        unsigned excl = 0;
        int waveBase = (team & 3) * 16;
        for (int k = 0; k < 16; ++k) {
            unsigned v = __shfl(ls, waveBase + k, 64);
            if (k < j) excl += v;
        }
        unsigned run = bstart[team] + excl;
        for (int b = j * per; b < (j + 1) * per; ++b) {
            offsets[(size_t)b * NPART + team] = run;
            run += blockHist[(size_t)b * NPART + team];
        }
    }
}

// Emit 16B records {s|d<<16, a, w, b} into partition bins (2 records if cross).
__global__ __launch_bounds__(TPB)
void scatter_kernel(const int* __restrict__ src, const int* __restrict__ des,
                    const float* __restrict__ param, const unsigned* __restrict__ offsets,
                    uint4* __restrict__ records, int E) {
    __shared__ unsigned offs[NPART];
    int tid = threadIdx.x;
    if (tid < NPART) offs[tid] = offsets[(size_t)blockIdx.x * NPART + tid];
    __syncthreads();
    long t = (long)blockIdx.x * TPB + tid;
    long stride = (long)gridDim.x * TPB * 4;
    for (long e0 = t * 4; e0 < E; e0 += stride) {
        int ne = (int)min((long)4, (long)E - e0);
        int ss[4], dd[4];
        float aa[4], ww[4], cc[4];
        if (ne == 4) {
            int4 sv = *(const int4*)(src + e0);
            int4 dv = *(const int4*)(des + e0);
            float4 av = *(const float4*)(param + e0);
            float4 wv = *(const float4*)(param + E + e0);
            float4 cv = *(const float4*)(param + 2 * (size_t)E + e0);
            ss[0]=sv.x; ss[1]=sv.y; ss[2]=sv.z; ss[3]=sv.w;
            dd[0]=dv.x; dd[1]=dv.y; dd[2]=dv.z; dd[3]=dv.w;
            aa[0]=av.x; aa[1]=av.y; aa[2]=av.z; aa[3]=av.w;
            ww[0]=wv.x; ww[1]=wv.y; ww[2]=wv.z; ww[3]=wv.w;
            cc[0]=cv.x; cc[1]=cv.y; cc[2]=cv.z; cc[3]=cv.w;
        } else {
            for (int j = 0; j < ne; ++j) {
                ss[j] = src[e0 + j]; dd[j] = des[e0 + j];
                aa[j] = param[e0 + j]; ww[j] = param[E + e0 + j];
                cc[j] = param[2 * (size_t)E + e0 + j];
            }
        }
        for (int j = 0; j < ne; ++j) {
            int s = ss[j], d = dd[j];
            uint4 rec = make_uint4((unsigned)s | ((unsigned)d << 16),
                                   __float_as_uint(aa[j]), __float_as_uint(ww[j]),
                                   __float_as_uint(cc[j]));
            int ps = s / PS, pd = d / PS;
            unsigned slot = atomicAdd(&offs[ps], 1u);
            records[slot] = rec;
            if (pd != ps) {
                unsigned slot2 = atomicAdd(&offs[pd], 1u);
                records[slot2] = rec;
            }
        }
    }
}

// Block (p, slice): stream record range, LDS-accumulate, dump partial.
__global__ __launch_bounds__(TPB)
void accumulate_kernel(const uint4* __restrict__ records, const float* __restrict__ auxT,
                       const unsigned* __restrict__ binStart,
                       const unsigned* __restrict__ binTotal,
                       float* __restrict__ partials) {
    __shared__ float acc[PS * BATCH];
    int p = blockIdx.x / SLICES;
    int sl = blockIdx.x % SLICES;
    int tid = threadIdx.x;
    for (int i = tid; i < PS * BATCH; i += TPB) acc[i] = 0.0f;
    __syncthreads();
    unsigned bs = binStart[p], cnt = binTotal[p];
    unsigned lo = bs + (unsigned)(((unsigned long long)cnt * sl) / SLICES);
    unsigned hi = bs + (unsigned)(((unsigned long long)cnt * (sl + 1)) / SLICES);
    int base = p * PS;
    int group = tid >> 4, b = tid & 15;
    for (unsigned r = lo + group; r < hi; r += TPB / 16) {
        uint4 rec = records[r];
        int s = (int)(rec.x & 0xFFFFu);
        int d = (int)(rec.x >> 16);
        float a = __uint_as_float(rec.y);
        float w = __uint_as_float(rec.z);
        float c = __uint_as_float(rec.w);
        float vs = auxT[s * BATCH + b];
        float vd = auxT[d * BATCH + b];
        float st = a * fast_tanh(w * (vs - vd) + c);
        unsigned ls = (unsigned)(s - base), ld = (unsigned)(d - base);
        if (ls < PS) atomicAdd(&acc[ls * BATCH + b], -st);
        if (ld < PS) atomicAdd(&acc[ld * BATCH + b], st);
    }
    __syncthreads();
    float* myPart = partials + (size_t)blockIdx.x * (PS * BATCH);
    for (int i = tid; i < PS * BATCH; i += TPB) myPart[i] = acc[i];
}

// out[b][j] = sum_sl partials[p*SLICES+sl][local][b], i=j+1
__global__ void reduce_sorted(const float* __restrict__ partials,
                              float* __restrict__ out, int n) {
    int idx = blockIdx.x * blockDim.x + threadIdx.x;
    if (idx >= BATCH * n) return;
    int b = idx / n;
    int j = idx % n;
    int i = j + 1;
    int p = i / PS;
    int local = i - p * PS;
    const float* basep = partials + (size_t)p * SLICES * (PS * BATCH)
                         + (size_t)local * BATCH + b;
    float sum = 0.0f;
#pragma unroll
    for (int sl = 0; sl < SLICES; ++sl) sum += basep[(size_t)sl * (PS * BATCH)];
    out[idx] = sum;
}

// ---------------- round-3 fallback: partition rescan ----------------
#define QCAP 768
#define SCAN_THREADS 1024
#define EPT 4

__global__ __launch_bounds__(SCAN_THREADS)
void scan_partition(const float* __restrict__ param,
                    const int* __restrict__ src,
                    const int* __restrict__ des,
                    const float* __restrict__ auxT,
                    float* __restrict__ partials,
                    int E, int Bp) {
    __shared__ float acc[PS * BATCH];
    __shared__ uint2 queue[QCAP];
    __shared__ int qc[2];
    const int p = blockIdx.x / Bp;
    const int k = blockIdx.x - p * Bp;
    const int base = p * PS;
    const int tid = threadIdx.x;
    const int lane = tid & 63;
    for (int i = tid; i < PS * BATCH; i += SCAN_THREADS) acc[i] = 0.0f;
    if (tid < 2) qc[tid] = 0;
    __syncthreads();
    const int chunkE = (((E + Bp - 1) / Bp) + 3) & ~3;
    const int start = k * chunkE;
    const int end = min(start + chunkE, E);
    const int iters = (chunkE + SCAN_THREADS * EPT - 1) / (SCAN_THREADS * EPT);
    int par = 0;
    for (int it = 0; it < iters; ++it) {
        int e0 = start + it * SCAN_THREADS * EPT + tid * EPT;
        int s4[EPT], d4[EPT];
        int nval = 0;
        if (e0 + EPT <= end) {
            int4 sv = *(const int4*)(src + e0);
            int4 dv = *(const int4*)(des + e0);
            s4[0]=sv.x; s4[1]=sv.y; s4[2]=sv.z; s4[3]=sv.w;
            d4[0]=dv.x; d4[1]=dv.y; d4[2]=dv.z; d4[3]=dv.w;
            nval = EPT;
        } else if (e0 < end) {
            nval = end - e0;
            for (int j = 0; j < nval; ++j) { s4[j] = src[e0 + j]; d4[j] = des[e0 + j]; }
        }
#pragma unroll
        for (int j = 0; j < EPT; ++j) {
            int s = s4[j], d = d4[j];
            bool ms = (j < nval) && ((unsigned)(s - base) < (unsigned)PS);
            bool md = (j < nval) && ((unsigned)(d - base) < (unsigned)PS);
            bool m = ms || md;
            unsigned long long mask = __ballot(m);
            if (mask) {
                int leader = __ffsll((long long)mask) - 1;
                int cnt = __popcll(mask);
                int qbase = 0;
                if (lane == leader) qbase = atomicAdd(&qc[par], cnt);
                qbase = __shfl(qbase, leader);
                if (m) {
                    int pos = qbase + __popcll(mask & ((1ull << lane) - 1ull));
                    if (pos < QCAP) {
                        int e = e0 + j;
                        unsigned idf = (unsigned)e | (ms ? 1u << 30 : 0u) | (md ? 1u << 31 : 0u);
                        queue[pos] = make_uint2(idf, (unsigned)s | ((unsigned)d << 16));
                    } else {
                        int e = e0 + j;
                        float a = param[e], w = param[E + e], cc = param[2 * E + e];
                        for (int b = 0; b < BATCH; ++b) {
                            float vs = auxT[s * BATCH + b];
                            float vd = auxT[d * BATCH + b];
                            float st = a * fast_tanh(w * (vs - vd) + cc);
                            if (ms) atomicAdd(&acc[(s - base) * BATCH + b], -st);
                            if (md) atomicAdd(&acc[(d - base) * BATCH + b], st);
                        }
                    }
                }
            }
        }
        __syncthreads();
        if (tid == 0) qc[par ^ 1] = 0;
        int Q = min(qc[par], QCAP);
        int group = tid >> 4;
        int b = tid & 15;
        for (int q = group; q < Q; q += SCAN_THREADS / 16) {
            uint2 r = queue[q];
            int s = (int)(r.y & 0xFFFFu);
            int d = (int)(r.y >> 16);
            int e = (int)(r.x & 0x0FFFFFFFu);
            float a = param[e], w = param[E + e], cc = param[2 * E + e];
            float vs = auxT[s * BATCH + b];
            float vd = auxT[d * BATCH + b];
            float st = a * fast_tanh(w * (vs - vd) + cc);
            if (r.x & (1u << 30)) atomicAdd(&acc[(s - base) * BATCH + b], -st);
            if (r.x & (1u << 31)) atomicAdd(&acc[(d - base) * BATCH + b], st);
        }
        __syncthreads();
        par ^= 1;
    }
    float* myPart = partials + (size_t)blockIdx.x * (PS * BATCH);
    for (int i = tid; i < PS * BATCH; i += SCAN_THREADS) myPart[i] = acc[i];
}

__global__ void reduce_partials(const float* __restrict__ partials,
                                float* __restrict__ out, int n, int Bp) {
    int idx = blockIdx.x * blockDim.x + threadIdx.x;
    if (idx >= BATCH * n) return;
    int b = idx / n;
    int j = idx % n;
    int i = j + 1;
    int p = i / PS;
    int local = i - p * PS;
    size_t off = (size_t)local * BATCH + b;
    const float* basep = partials + (size_t)p * Bp * (PS * BATCH);
    float sum = 0.0f;
    for (int k = 0; k < Bp; ++k) sum += basep[(size_t)k * (PS * BATCH) + off];
    out[idx] = sum;
}

__global__ void edge_direct(const float* __restrict__ param,
                            const int* __restrict__ src,
                            const int* __restrict__ des,
                            const float* __restrict__ x,
                            float* __restrict__ out, int E, int n) {
    int e = blockIdx.x * blockDim.x + threadIdx.x;
    if (e >= E) return;
    float a = param[e], w = param[E + e], c = param[2 * E + e];
    int s = src[e], d = des[e];
#pragma unroll
    for (int b = 0; b < BATCH; ++b) {
        float vs = s ? x[(size_t)b * n + (s - 1)] : 0.0f;
        float vd = d ? x[(size_t)b * n + (d - 1)] : 0.0f;
        float st = a * tanhf(w * (vs - vd) + c);
        if (s) atomicAdd(out + (size_t)b * n + (s - 1), -st);
        if (d) atomicAdd(out + (size_t)b * n + (d - 1), st);
    }
}

extern "C" void kernel_launch(void* const* d_in, const int* in_sizes, int n_in,
                              void* d_out, int out_size, void* d_ws, size_t ws_size,
                              hipStream_t stream) {
    const float* x     = (const float*)d_in[1];
    const float* param = (const float*)d_in[2];
    const int*   src   = (const int*)d_in[3];
    const int*   des   = (const int*)d_in[4];
    float* out = (float*)d_out;

    int E = in_sizes[3];
    int n = in_sizes[1] / BATCH;   // N = 50000
    int total = BATCH * n;

    auto alignup = [](size_t v) { return (v + 255) & ~(size_t)255; };
    size_t auxBytes     = alignup((size_t)(n + 1) * BATCH * sizeof(float));
    size_t recBytes     = alignup((size_t)2 * E * sizeof(uint4));
    size_t histBytes    = alignup((size_t)NB * NPART * sizeof(unsigned));
    size_t offBytes     = histBytes;
    size_t binBytes     = alignup((size_t)NPART * sizeof(unsigned));
    size_t partBytes    = alignup((size_t)NB * PS * BATCH * sizeof(float));
    size_t needSorted   = auxBytes + recBytes + histBytes + offBytes + 2 * binBytes + partBytes;

    if (ws_size >= needSorted && (n + 1) <= NPART * PS && n <= 65535) {
        char* w = (char*)d_ws;
        float*    auxT      = (float*)w;                 w += auxBytes;
        uint4*    records   = (uint4*)w;                 w += recBytes;
        unsigned* blockHist = (unsigned*)w;              w += histBytes;
        unsigned* offsets   = (unsigned*)w;              w += offBytes;
        unsigned* binStart  = (unsigned*)w;              w += binBytes;
        unsigned* binTotal  = (unsigned*)w;              w += binBytes;
        float*    partials  = (float*)w;

        build_aux_T<<<(total + 255) / 256, 256, 0, stream>>>(x, auxT, n);
        hist_kernel<<<NB, TPB, 0, stream>>>(src, des, blockHist, E);
        scan_offsets<<<1, TPB, 0, stream>>>(blockHist, offsets, binStart, binTotal);
        scatter_kernel<<<NB, TPB, 0, stream>>>(src, des, param, offsets, records, E);
        accumulate_kernel<<<NB, TPB, 0, stream>>>(records, auxT, binStart, binTotal, partials);
        reduce_sorted<<<(total + 255) / 256, 256, 0, stream>>>(partials, out, n);
        return;
    }

    // fallback: round-3 partition-rescan
    size_t partialPerBp = (size_t)NPART * PS * BATCH * sizeof(float);
    int Bp = 0;
    if (ws_size > auxBytes) Bp = (int)((ws_size - auxBytes) / partialPerBp);
    if (Bp > 10) Bp = 10;

    if (Bp >= 1 && (n + 1) <= NPART * PS) {
        float* auxT = (float*)d_ws;
        float* partials = (float*)((char*)d_ws + auxBytes);
        build_aux_T<<<(total + 255) / 256, 256, 0, stream>>>(x, auxT, n);
        scan_partition<<<NPART * Bp, SCAN_THREADS, 0, stream>>>(param, src, des,
                                                                auxT, partials, E, Bp);
        reduce_partials<<<(total + 255) / 256, 256, 0, stream>>>(partials, out, n, Bp);
    } else {
        hipMemsetAsync(out, 0, (size_t)out_size * sizeof(float), stream);
        edge_direct<<<(E + 255) / 256, 256, 0, stream>>>(param, src, des, x, out, E, n);
    }
}

// Round 6
// 437.646 us; speedup vs baseline: 5.9751x; 1.0064x over previous
//
#include <hip/hip_runtime.h>

#define BATCH 16
#define PS 896          // nodes per partition (LDS acc = 896*16*4 = 57344 B)
#define NPART 56        // ceil(50001/896)
#define SLICES 8        // accumulate blocks per partition
#define NB (NPART * SLICES)   // 448 blocks for hist/scatter/accumulate
#define TPB 1024

typedef unsigned int uint4v __attribute__((ext_vector_type(4)));

// fast tanh: 1 - 2/(e^{2z}+1); rel err ~1e-6 vs 2.6e-4 threshold
static __device__ __forceinline__ float fast_tanh(float z) {
    float ez = __expf(2.0f * z);
    return 1.0f - 2.0f * __builtin_amdgcn_rcpf(ez + 1.0f);
}

// aux_T[(N+1)][16]: node-major transpose of x with a zero row at node 0.
__global__ void build_aux_T(const float* __restrict__ x, float* __restrict__ auxT, int n) {
    int idx = blockIdx.x * blockDim.x + threadIdx.x;
    if (idx >= BATCH * n) return;
    int b = idx / n;
    int i = idx % n;
    auxT[(i + 1) * BATCH + b] = x[idx];
    if (idx < BATCH) auxT[idx] = 0.0f;
}

// ---------------- sorted-record path ----------------

__global__ __launch_bounds__(TPB)
void hist_kernel(const int* __restrict__ src, const int* __restrict__ des,
                 unsigned* __restrict__ blockHist, int E) {
    __shared__ unsigned hist[NPART];
    int tid = threadIdx.x;
    for (int i = tid; i < NPART; i += TPB) hist[i] = 0;
    __syncthreads();
    long t = (long)blockIdx.x * TPB + tid;
    long stride = (long)gridDim.x * TPB * 4;
    for (long e0 = t * 4; e0 < E; e0 += stride) {
        int ne = (int)min((long)4, (long)E - e0);
        if (ne == 4) {
            int4 sv = *(const int4*)(src + e0);
            int4 dv = *(const int4*)(des + e0);
            int ss[4] = {sv.x, sv.y, sv.z, sv.w};
            int dd[4] = {dv.x, dv.y, dv.z, dv.w};
#pragma unroll
            for (int j = 0; j < 4; ++j) {
                int ps = ss[j] / PS, pd = dd[j] / PS;
                atomicAdd(&hist[ps], 1u);
                if (pd != ps) atomicAdd(&hist[pd], 1u);
            }
        } else {
            for (int j = 0; j < ne; ++j) {
                int ps = src[e0 + j] / PS, pd = des[e0 + j] / PS;
                atomicAdd(&hist[ps], 1u);
                if (pd != ps) atomicAdd(&hist[pd], 1u);
            }
        }
    }
    __syncthreads();
    if (tid < NPART) blockHist[(size_t)blockIdx.x * NPART + tid] = hist[tid];
}

// One block: exact scatter offsets per (block, partition). NB must be /16.
__global__ __launch_bounds__(TPB)
void scan_offsets(const unsigned* __restrict__ blockHist, unsigned* __restrict__ offsets,
                  unsigned* __restrict__ binStartG, unsigned* __restrict__ binTotalG) {
    __shared__ unsigned tot[NPART];
    __shared__ unsigned bstart[NPART];
    int tid = threadIdx.x;
    int team = tid >> 4, j = tid & 15;
    if (team < NPART) {
        unsigned lsum = 0;
        for (int b = j; b < NB; b += 16) lsum += blockHist[(size_t)b * NPART + team];
        for (int m = 1; m < 16; m <<= 1) lsum += __shfl_xor(lsum, m, 64);
        if (j == 0) tot[team] = lsum;
    }
    __syncthreads();
    if (tid == 0) {
        unsigned run = 0;
        for (int p = 0; p < NPART; ++p) { bstart[p] = run; run += tot[p]; }
    }
    __syncthreads();
    if (tid < NPART) { binStartG[tid] = bstart[tid]; binTotalG[tid] = tot[tid]; }
    if (team < NPART) {
        const int per = NB / 16;   // 28
        unsigned ls = 0;
        for (int b = j * per; b < (j + 1) * per; ++b)
            ls += blockHist[(size_t)b * NPART + team];
        unsigned excl = 0;
        int waveBase = (team & 3) * 16;
        for (int k = 0; k < 16; ++k) {
            unsigned v = __shfl(ls, waveBase + k, 64);
            if (k < j) excl += v;
        }
        unsigned run = bstart[team] + excl;
        for (int b = j * per; b < (j + 1) * per; ++b) {
            offsets[(size_t)b * NPART + team] = run;
            run += blockHist[(size_t)b * NPART + team];
        }
    }
}

// Emit 16B records {s|d<<16, a, w, b} into partition bins (2 records if cross).
__global__ __launch_bounds__(TPB)
void scatter_kernel(const int* __restrict__ src, const int* __restrict__ des,
                    const float* __restrict__ param, const unsigned* __restrict__ offsets,
                    uint4* __restrict__ records, int E) {
    __shared__ unsigned offs[NPART];
    int tid = threadIdx.x;
    if (tid < NPART) offs[tid] = offsets[(size_t)blockIdx.x * NPART + tid];
    __syncthreads();
    long t = (long)blockIdx.x * TPB + tid;
    long stride = (long)gridDim.x * TPB * 4;
    for (long e0 = t * 4; e0 < E; e0 += stride) {
        int ne = (int)min((long)4, (long)E - e0);
        int ss[4], dd[4];
        float aa[4], ww[4], cc[4];
        if (ne == 4) {
            int4 sv = *(const int4*)(src + e0);
            int4 dv = *(const int4*)(des + e0);
            float4 av = *(const float4*)(param + e0);
            float4 wv = *(const float4*)(param + E + e0);
            float4 cv = *(const float4*)(param + 2 * (size_t)E + e0);
            ss[0]=sv.x; ss[1]=sv.y; ss[2]=sv.z; ss[3]=sv.w;
            dd[0]=dv.x; dd[1]=dv.y; dd[2]=dv.z; dd[3]=dv.w;
            aa[0]=av.x; aa[1]=av.y; aa[2]=av.z; aa[3]=av.w;
            ww[0]=wv.x; ww[1]=wv.y; ww[2]=wv.z; ww[3]=wv.w;
            cc[0]=cv.x; cc[1]=cv.y; cc[2]=cv.z; cc[3]=cv.w;
        } else {
            for (int j = 0; j < ne; ++j) {
                ss[j] = src[e0 + j]; dd[j] = des[e0 + j];
                aa[j] = param[e0 + j]; ww[j] = param[E + e0 + j];
                cc[j] = param[2 * (size_t)E + e0 + j];
            }
        }
        for (int j = 0; j < ne; ++j) {
            int s = ss[j], d = dd[j];
            uint4 rec = make_uint4((unsigned)s | ((unsigned)d << 16),
                                   __float_as_uint(aa[j]), __float_as_uint(ww[j]),
                                   __float_as_uint(cc[j]));
            int ps = s / PS, pd = d / PS;
            unsigned slot = atomicAdd(&offs[ps], 1u);
            records[slot] = rec;
            if (pd != ps) {
                unsigned slot2 = atomicAdd(&offs[pd], 1u);
                records[slot2] = rec;
            }
        }
    }
}

// Block (p, slice): stream record range with 4-deep MLP, LDS-accumulate, dump partial.
__global__ __launch_bounds__(TPB)
void accumulate_kernel(const uint4* __restrict__ records, const float* __restrict__ auxT,
                       const unsigned* __restrict__ binStart,
                       const unsigned* __restrict__ binTotal,
                       float* __restrict__ partials) {
    __shared__ float acc[PS * BATCH];
    int p = blockIdx.x / SLICES;
    int sl = blockIdx.x % SLICES;
    int tid = threadIdx.x;
    for (int i = tid; i < PS * BATCH; i += TPB) acc[i] = 0.0f;
    __syncthreads();
    unsigned bs = binStart[p], cnt = binTotal[p];
    unsigned lo = bs + (unsigned)(((unsigned long long)cnt * sl) / SLICES);
    unsigned hi = bs + (unsigned)(((unsigned long long)cnt * (sl + 1)) / SLICES);
    int base = p * PS;
    int group = tid >> 4, b = tid & 15;
    const unsigned G = TPB / 16;   // 64 groups
    const uint4v* recv = (const uint4v*)records;

    unsigned r = lo + group;
    // ---- 4-deep unrolled main loop: 4 records in flight per group ----
    for (; r + 3 * G < hi; r += 4 * G) {
        uint4v rec0 = __builtin_nontemporal_load(&recv[r]);
        uint4v rec1 = __builtin_nontemporal_load(&recv[r + G]);
        uint4v rec2 = __builtin_nontemporal_load(&recv[r + 2 * G]);
        uint4v rec3 = __builtin_nontemporal_load(&recv[r + 3 * G]);

        int s0 = (int)(rec0.x & 0xFFFFu), d0 = (int)(rec0.x >> 16);
        int s1 = (int)(rec1.x & 0xFFFFu), d1 = (int)(rec1.x >> 16);
        int s2 = (int)(rec2.x & 0xFFFFu), d2 = (int)(rec2.x >> 16);
        int s3 = (int)(rec3.x & 0xFFFFu), d3 = (int)(rec3.x >> 16);

        float vs0 = auxT[s0 * BATCH + b], vd0 = auxT[d0 * BATCH + b];
        float vs1 = auxT[s1 * BATCH + b], vd1 = auxT[d1 * BATCH + b];
        float vs2 = auxT[s2 * BATCH + b], vd2 = auxT[d2 * BATCH + b];
        float vs3 = auxT[s3 * BATCH + b], vd3 = auxT[d3 * BATCH + b];

        float st0 = __uint_as_float(rec0.y) *
                    fast_tanh(__uint_as_float(rec0.z) * (vs0 - vd0) + __uint_as_float(rec0.w));
        float st1 = __uint_as_float(rec1.y) *
                    fast_tanh(__uint_as_float(rec1.z) * (vs1 - vd1) + __uint_as_float(rec1.w));
        float st2 = __uint_as_float(rec2.y) *
                    fast_tanh(__uint_as_float(rec2.z) * (vs2 - vd2) + __uint_as_float(rec2.w));
        float st3 = __uint_as_float(rec3.y) *
                    fast_tanh(__uint_as_float(rec3.z) * (vs3 - vd3) + __uint_as_float(rec3.w));

        unsigned ls0 = (unsigned)(s0 - base), ld0 = (unsigned)(d0 - base);
        unsigned ls1 = (unsigned)(s1 - base), ld1 = (unsigned)(d1 - base);
        unsigned ls2 = (unsigned)(s2 - base), ld2 = (unsigned)(d2 - base);
        unsigned ls3 = (unsigned)(s3 - base), ld3 = (unsigned)(d3 - base);
        if (ls0 < PS) atomicAdd(&acc[ls0 * BATCH + b], -st0);
        if (ld0 < PS) atomicAdd(&acc[ld0 * BATCH + b],  st0);
        if (ls1 < PS) atomicAdd(&acc[ls1 * BATCH + b], -st1);
        if (ld1 < PS) atomicAdd(&acc[ld1 * BATCH + b],  st1);
        if (ls2 < PS) atomicAdd(&acc[ls2 * BATCH + b], -st2);
        if (ld2 < PS) atomicAdd(&acc[ld2 * BATCH + b],  st2);
        if (ls3 < PS) atomicAdd(&acc[ls3 * BATCH + b], -st3);
        if (ld3 < PS) atomicAdd(&acc[ld3 * BATCH + b],  st3);
    }
    // ---- tail ----
    for (; r < hi; r += G) {
        uint4 rec = records[r];
        int s = (int)(rec.x & 0xFFFFu);
        int d = (int)(rec.x >> 16);
        float vs = auxT[s * BATCH + b];
        float vd = auxT[d * BATCH + b];
        float st = __uint_as_float(rec.y) *
                   fast_tanh(__uint_as_float(rec.z) * (vs - vd) + __uint_as_float(rec.w));
        unsigned ls = (unsigned)(s - base), ld = (unsigned)(d - base);
        if (ls < PS) atomicAdd(&acc[ls * BATCH + b], -st);
        if (ld < PS) atomicAdd(&acc[ld * BATCH + b], st);
    }
    __syncthreads();
    float* myPart = partials + (size_t)blockIdx.x * (PS * BATCH);
    for (int i = tid; i < PS * BATCH; i += TPB) myPart[i] = acc[i];
}

// out[b][j] = sum_sl partials[p*SLICES+sl][local][b], i=j+1
__global__ void reduce_sorted(const float* __restrict__ partials,
                              float* __restrict__ out, int n) {
    int idx = blockIdx.x * blockDim.x + threadIdx.x;
    if (idx >= BATCH * n) return;
    int b = idx / n;
    int j = idx % n;
    int i = j + 1;
    int p = i / PS;
    int local = i - p * PS;
    const float* basep = partials + (size_t)p * SLICES * (PS * BATCH)
                         + (size_t)local * BATCH + b;
    float sum = 0.0f;
#pragma unroll
    for (int sl = 0; sl < SLICES; ++sl) sum += basep[(size_t)sl * (PS * BATCH)];
    out[idx] = sum;
}

// ---------------- fallback: direct device atomics ----------------
__global__ void edge_direct(const float* __restrict__ param,
                            const int* __restrict__ src,
                            const int* __restrict__ des,
                            const float* __restrict__ x,
                            float* __restrict__ out, int E, int n) {
    int e = blockIdx.x * blockDim.x + threadIdx.x;
    if (e >= E) return;
    float a = param[e], w = param[E + e], c = param[2 * E + e];
    int s = src[e], d = des[e];
#pragma unroll
    for (int b = 0; b < BATCH; ++b) {
        float vs = s ? x[(size_t)b * n + (s - 1)] : 0.0f;
        float vd = d ? x[(size_t)b * n + (d - 1)] : 0.0f;
        float st = a * tanhf(w * (vs - vd) + c);
        if (s) atomicAdd(out + (size_t)b * n + (s - 1), -st);
        if (d) atomicAdd(out + (size_t)b * n + (d - 1), st);
    }
}

extern "C" void kernel_launch(void* const* d_in, const int* in_sizes, int n_in,
                              void* d_out, int out_size, void* d_ws, size_t ws_size,
                              hipStream_t stream) {
    const float* x     = (const float*)d_in[1];
    const float* param = (const float*)d_in[2];
    const int*   src   = (const int*)d_in[3];
    const int*   des   = (const int*)d_in[4];
    float* out = (float*)d_out;

    int E = in_sizes[3];
    int n = in_sizes[1] / BATCH;   // N = 50000
    int total = BATCH * n;

    auto alignup = [](size_t v) { return (v + 255) & ~(size_t)255; };
    size_t auxBytes     = alignup((size_t)(n + 1) * BATCH * sizeof(float));
    size_t recBytes     = alignup((size_t)2 * E * sizeof(uint4));
    size_t histBytes    = alignup((size_t)NB * NPART * sizeof(unsigned));
    size_t offBytes     = histBytes;
    size_t binBytes     = alignup((size_t)NPART * sizeof(unsigned));
    size_t partBytes    = alignup((size_t)NB * PS * BATCH * sizeof(float));
    size_t needSorted   = auxBytes + recBytes + histBytes + offBytes + 2 * binBytes + partBytes;

    if (ws_size >= needSorted && (n + 1) <= NPART * PS && n <= 65535) {
        char* w = (char*)d_ws;
        float*    auxT      = (float*)w;                 w += auxBytes;
        uint4*    records   = (uint4*)w;                 w += recBytes;
        unsigned* blockHist = (unsigned*)w;              w += histBytes;
        unsigned* offsets   = (unsigned*)w;              w += offBytes;
        unsigned* binStart  = (unsigned*)w;              w += binBytes;
        unsigned* binTotal  = (unsigned*)w;              w += binBytes;
        float*    partials  = (float*)w;

        build_aux_T<<<(total + 255) / 256, 256, 0, stream>>>(x, auxT, n);
        hist_kernel<<<NB, TPB, 0, stream>>>(src, des, blockHist, E);
        scan_offsets<<<1, TPB, 0, stream>>>(blockHist, offsets, binStart, binTotal);
        scatter_kernel<<<NB, TPB, 0, stream>>>(src, des, param, offsets, records, E);
        accumulate_kernel<<<NB, TPB, 0, stream>>>(records, auxT, binStart, binTotal, partials);
        reduce_sorted<<<(total + 255) / 256, 256, 0, stream>>>(partials, out, n);
        return;
    }

    (void)hipMemsetAsync(out, 0, (size_t)out_size * sizeof(float), stream);
    edge_direct<<<(E + 255) / 256, 256, 0, stream>>>(param, src, des, x, out, E, n);
}

// Round 7
// 407.454 us; speedup vs baseline: 6.4178x; 1.0741x over previous
//
#include <hip/hip_runtime.h>

#define BATCH 16
#define PS 784          // nodes per partition; LDS acc = 784*17*4 = 53312 B
#define STRIDE 17       // padded per-node LDS stride (floats) to spread banks
#define NPART 64        // 64*784 = 50176 >= 50001
#define SLICES 8        // accumulate blocks per partition
#define NB (NPART * SLICES)   // 512 blocks = exactly 2/CU
#define TPB 1024

typedef unsigned int uint4v __attribute__((ext_vector_type(4)));

// fast tanh: 1 - 2/(e^{2z}+1); rel err ~1e-6 vs 2.6e-4 threshold
static __device__ __forceinline__ float fast_tanh(float z) {
    float ez = __expf(2.0f * z);
    return 1.0f - 2.0f * __builtin_amdgcn_rcpf(ez + 1.0f);
}

// aux_T[(N+1)][16]: node-major transpose of x with a zero row at node 0.
__global__ void build_aux_T(const float* __restrict__ x, float* __restrict__ auxT, int n) {
    int idx = blockIdx.x * blockDim.x + threadIdx.x;
    if (idx >= BATCH * n) return;
    int b = idx / n;
    int i = idx % n;
    auxT[(i + 1) * BATCH + b] = x[idx];
    if (idx < BATCH) auxT[idx] = 0.0f;
}

// ---------------- sorted-record path ----------------

__global__ __launch_bounds__(TPB)
void hist_kernel(const int* __restrict__ src, const int* __restrict__ des,
                 unsigned* __restrict__ blockHist, int E) {
    __shared__ unsigned hist[NPART];
    int tid = threadIdx.x;
    for (int i = tid; i < NPART; i += TPB) hist[i] = 0;
    __syncthreads();
    long t = (long)blockIdx.x * TPB + tid;
    long stride = (long)gridDim.x * TPB * 4;
    for (long e0 = t * 4; e0 < E; e0 += stride) {
        int ne = (int)min((long)4, (long)E - e0);
        if (ne == 4) {
            int4 sv = *(const int4*)(src + e0);
            int4 dv = *(const int4*)(des + e0);
            int ss[4] = {sv.x, sv.y, sv.z, sv.w};
            int dd[4] = {dv.x, dv.y, dv.z, dv.w};
#pragma unroll
            for (int j = 0; j < 4; ++j) {
                int ps = ss[j] / PS, pd = dd[j] / PS;
                atomicAdd(&hist[ps], 1u);
                if (pd != ps) atomicAdd(&hist[pd], 1u);
            }
        } else {
            for (int j = 0; j < ne; ++j) {
                int ps = src[e0 + j] / PS, pd = des[e0 + j] / PS;
                atomicAdd(&hist[ps], 1u);
                if (pd != ps) atomicAdd(&hist[pd], 1u);
            }
        }
    }
    __syncthreads();
    if (tid < NPART) blockHist[(size_t)blockIdx.x * NPART + tid] = hist[tid];
}

// One block: exact scatter offsets per (block, partition). NB/16 must be int.
__global__ __launch_bounds__(TPB)
void scan_offsets(const unsigned* __restrict__ blockHist, unsigned* __restrict__ offsets,
                  unsigned* __restrict__ binStartG, unsigned* __restrict__ binTotalG) {
    __shared__ unsigned tot[NPART];
    __shared__ unsigned bstart[NPART];
    int tid = threadIdx.x;
    int team = tid >> 4, j = tid & 15;   // 64 teams of 16 = TPB
    if (team < NPART) {
        unsigned lsum = 0;
        for (int b = j; b < NB; b += 16) lsum += blockHist[(size_t)b * NPART + team];
        for (int m = 1; m < 16; m <<= 1) lsum += __shfl_xor(lsum, m, 64);
        if (j == 0) tot[team] = lsum;
    }
    __syncthreads();
    if (tid == 0) {
        unsigned run = 0;
        for (int p = 0; p < NPART; ++p) { bstart[p] = run; run += tot[p]; }
    }
    __syncthreads();
    if (tid < NPART) { binStartG[tid] = bstart[tid]; binTotalG[tid] = tot[tid]; }
    if (team < NPART) {
        const int per = NB / 16;   // 32
        unsigned ls = 0;
        for (int b = j * per; b < (j + 1) * per; ++b)
            ls += blockHist[(size_t)b * NPART + team];
        unsigned excl = 0;
        int waveBase = (team & 3) * 16;
        for (int k = 0; k < 16; ++k) {
            unsigned v = __shfl(ls, waveBase + k, 64);
            if (k < j) excl += v;
        }
        unsigned run = bstart[team] + excl;
        for (int b = j * per; b < (j + 1) * per; ++b) {
            offsets[(size_t)b * NPART + team] = run;
            run += blockHist[(size_t)b * NPART + team];
        }
    }
}

// Emit 16B records {s|d<<16, a, w, b} into partition bins (2 records if cross).
__global__ __launch_bounds__(TPB)
void scatter_kernel(const int* __restrict__ src, const int* __restrict__ des,
                    const float* __restrict__ param, const unsigned* __restrict__ offsets,
                    uint4* __restrict__ records, int E) {
    __shared__ unsigned offs[NPART];
    int tid = threadIdx.x;
    if (tid < NPART) offs[tid] = offsets[(size_t)blockIdx.x * NPART + tid];
    __syncthreads();
    long t = (long)blockIdx.x * TPB + tid;
    long stride = (long)gridDim.x * TPB * 4;
    for (long e0 = t * 4; e0 < E; e0 += stride) {
        int ne = (int)min((long)4, (long)E - e0);
        int ss[4], dd[4];
        float aa[4], ww[4], cc[4];
        if (ne == 4) {
            int4 sv = *(const int4*)(src + e0);
            int4 dv = *(const int4*)(des + e0);
            float4 av = *(const float4*)(param + e0);
            float4 wv = *(const float4*)(param + E + e0);
            float4 cv = *(const float4*)(param + 2 * (size_t)E + e0);
            ss[0]=sv.x; ss[1]=sv.y; ss[2]=sv.z; ss[3]=sv.w;
            dd[0]=dv.x; dd[1]=dv.y; dd[2]=dv.z; dd[3]=dv.w;
            aa[0]=av.x; aa[1]=av.y; aa[2]=av.z; aa[3]=av.w;
            ww[0]=wv.x; ww[1]=wv.y; ww[2]=wv.z; ww[3]=wv.w;
            cc[0]=cv.x; cc[1]=cv.y; cc[2]=cv.z; cc[3]=cv.w;
        } else {
            for (int j = 0; j < ne; ++j) {
                ss[j] = src[e0 + j]; dd[j] = des[e0 + j];
                aa[j] = param[e0 + j]; ww[j] = param[E + e0 + j];
                cc[j] = param[2 * (size_t)E + e0 + j];
            }
        }
        for (int j = 0; j < ne; ++j) {
            int s = ss[j], d = dd[j];
            uint4 rec = make_uint4((unsigned)s | ((unsigned)d << 16),
                                   __float_as_uint(aa[j]), __float_as_uint(ww[j]),
                                   __float_as_uint(cc[j]));
            int ps = s / PS, pd = d / PS;
            unsigned slot = atomicAdd(&offs[ps], 1u);
            records[slot] = rec;
            if (pd != ps) {
                unsigned slot2 = atomicAdd(&offs[pd], 1u);
                records[slot2] = rec;
            }
        }
    }
}

// Block (p, slice): 4 lanes per record, each lane owns 4 batches (float4).
// VMEM inst per record: 1/16 rec + 2/16 aux = 0.19 (was 3.0).
__global__ __launch_bounds__(TPB, 8)
void accumulate_kernel(const uint4* __restrict__ records, const float* __restrict__ auxT,
                       const unsigned* __restrict__ binStart,
                       const unsigned* __restrict__ binTotal,
                       float* __restrict__ partials) {
    __shared__ float acc[PS * STRIDE];
    int p = blockIdx.x >> 3;          // / SLICES
    int sl = blockIdx.x & (SLICES - 1);
    int tid = threadIdx.x;
    for (int i = tid; i < PS * STRIDE; i += TPB) acc[i] = 0.0f;
    __syncthreads();
    unsigned bs = binStart[p], cnt = binTotal[p];
    unsigned lo = bs + (unsigned)(((unsigned long long)cnt * sl) / SLICES);
    unsigned hi = bs + (unsigned)(((unsigned long long)cnt * (sl + 1)) / SLICES);
    int base = p * PS;
    int g = tid >> 2;                 // 256 groups of 4 lanes
    int lj = tid & 3;                 // lane-in-group: batches 4*lj .. 4*lj+3
    const unsigned G = TPB / 4;       // 256
    const uint4v* recv = (const uint4v*)records;
    const float4* aux4 = (const float4*)auxT;   // row i = aux4[i*4 + lj]
    int bb = lj * 4;

    for (unsigned r = lo + g; r < hi; r += G) {
        uint4v rec = __builtin_nontemporal_load(&recv[r]);
        int s = (int)(rec.x & 0xFFFFu);
        int d = (int)(rec.x >> 16);
        float4 vs = aux4[s * 4 + lj];
        float4 vd = aux4[d * 4 + lj];
        float a = __uint_as_float(rec.y);
        float w = __uint_as_float(rec.z);
        float c = __uint_as_float(rec.w);
        float st0 = a * fast_tanh(w * (vs.x - vd.x) + c);
        float st1 = a * fast_tanh(w * (vs.y - vd.y) + c);
        float st2 = a * fast_tanh(w * (vs.z - vd.z) + c);
        float st3 = a * fast_tanh(w * (vs.w - vd.w) + c);
        unsigned ls = (unsigned)(s - base), ld = (unsigned)(d - base);
        if (ls < PS) {
            float* as_ = &acc[ls * STRIDE + bb];
            atomicAdd(as_ + 0, -st0);
            atomicAdd(as_ + 1, -st1);
            atomicAdd(as_ + 2, -st2);
            atomicAdd(as_ + 3, -st3);
        }
        if (ld < PS) {
            float* ad_ = &acc[ld * STRIDE + bb];
            atomicAdd(ad_ + 0, st0);
            atomicAdd(ad_ + 1, st1);
            atomicAdd(ad_ + 2, st2);
            atomicAdd(ad_ + 3, st3);
        }
    }
    __syncthreads();
    float* myPart = partials + (size_t)blockIdx.x * (PS * BATCH);
    for (int i = tid; i < PS * BATCH; i += TPB)
        myPart[i] = acc[(i >> 4) * STRIDE + (i & 15)];
}

// out[b][j] = sum_sl partials[p*SLICES+sl][local*16+b], node i=j+1
__global__ void reduce_sorted(const float* __restrict__ partials,
                              float* __restrict__ out, int n) {
    int idx = blockIdx.x * blockDim.x + threadIdx.x;
    if (idx >= BATCH * n) return;
    int b = idx / n;
    int j = idx % n;
    int i = j + 1;
    int p = i / PS;
    int local = i - p * PS;
    const float* basep = partials + (size_t)p * SLICES * (PS * BATCH)
                         + (size_t)local * BATCH + b;
    float sum = 0.0f;
#pragma unroll
    for (int sl = 0; sl < SLICES; ++sl) sum += basep[(size_t)sl * (PS * BATCH)];
    out[idx] = sum;
}

// ---------------- fallback: direct device atomics ----------------
__global__ void edge_direct(const float* __restrict__ param,
                            const int* __restrict__ src,
                            const int* __restrict__ des,
                            const float* __restrict__ x,
                            float* __restrict__ out, int E, int n) {
    int e = blockIdx.x * blockDim.x + threadIdx.x;
    if (e >= E) return;
    float a = param[e], w = param[E + e], c = param[2 * E + e];
    int s = src[e], d = des[e];
#pragma unroll
    for (int b = 0; b < BATCH; ++b) {
        float vs = s ? x[(size_t)b * n + (s - 1)] : 0.0f;
        float vd = d ? x[(size_t)b * n + (d - 1)] : 0.0f;
        float st = a * tanhf(w * (vs - vd) + c);
        if (s) atomicAdd(out + (size_t)b * n + (s - 1), -st);
        if (d) atomicAdd(out + (size_t)b * n + (d - 1), st);
    }
}

extern "C" void kernel_launch(void* const* d_in, const int* in_sizes, int n_in,
                              void* d_out, int out_size, void* d_ws, size_t ws_size,
                              hipStream_t stream) {
    const float* x     = (const float*)d_in[1];
    const float* param = (const float*)d_in[2];
    const int*   src   = (const int*)d_in[3];
    const int*   des   = (const int*)d_in[4];
    float* out = (float*)d_out;

    int E = in_sizes[3];
    int n = in_sizes[1] / BATCH;   // N = 50000
    int total = BATCH * n;

    auto alignup = [](size_t v) { return (v + 255) & ~(size_t)255; };
    size_t auxBytes     = alignup((size_t)(n + 1) * BATCH * sizeof(float));
    size_t recBytes     = alignup((size_t)2 * E * sizeof(uint4));
    size_t histBytes    = alignup((size_t)NB * NPART * sizeof(unsigned));
    size_t offBytes     = histBytes;
    size_t binBytes     = alignup((size_t)NPART * sizeof(unsigned));
    size_t partBytes    = alignup((size_t)NB * PS * BATCH * sizeof(float));
    size_t needSorted   = auxBytes + recBytes + histBytes + offBytes + 2 * binBytes + partBytes;

    if (ws_size >= needSorted && (n + 1) <= NPART * PS && n <= 65535) {
        char* w = (char*)d_ws;
        float*    auxT      = (float*)w;                 w += auxBytes;
        uint4*    records   = (uint4*)w;                 w += recBytes;
        unsigned* blockHist = (unsigned*)w;              w += histBytes;
        unsigned* offsets   = (unsigned*)w;              w += offBytes;
        unsigned* binStart  = (unsigned*)w;              w += binBytes;
        unsigned* binTotal  = (unsigned*)w;              w += binBytes;
        float*    partials  = (float*)w;

        build_aux_T<<<(total + 255) / 256, 256, 0, stream>>>(x, auxT, n);
        hist_kernel<<<NB, TPB, 0, stream>>>(src, des, blockHist, E);
        scan_offsets<<<1, TPB, 0, stream>>>(blockHist, offsets, binStart, binTotal);
        scatter_kernel<<<NB, TPB, 0, stream>>>(src, des, param, offsets, records, E);
        accumulate_kernel<<<NB, TPB, 0, stream>>>(records, auxT, binStart, binTotal, partials);
        reduce_sorted<<<(total + 255) / 256, 256, 0, stream>>>(partials, out, n);
        return;
    }

    (void)hipMemsetAsync(out, 0, (size_t)out_size * sizeof(float), stream);
    edge_direct<<<(E + 255) / 256, 256, 0, stream>>>(param, src, des, x, out, E, n);
}